// Round 8
// baseline (326.252 us; speedup 1.0000x reference)
//
#include <hip/hip_runtime.h>

#define DEV __device__ __forceinline__

typedef __attribute__((ext_vector_type(8))) short short8;
typedef __attribute__((ext_vector_type(4))) short short4v;
typedef __attribute__((ext_vector_type(4))) float f32x4;

// ---------- bf16 helpers ----------
DEV float bf2f(unsigned short u) { return __uint_as_float(((unsigned int)u) << 16); }
DEV unsigned short f2bf(float f) {
    unsigned int u = __float_as_uint(f);
    u += 0x7FFFu + ((u >> 16) & 1u);   // RNE
    return (unsigned short)(u >> 16);
}

DEV float elu1(float v) { return v > 0.0f ? v + 1.0f : __expf(v); }

// ---------- async global->LDS, 16B per lane ----------
DEV void gload_lds16(const void* g, void* l) {
    __builtin_amdgcn_global_load_lds(
        (__attribute__((address_space(1))) unsigned int*)(g),
        (__attribute__((address_space(3))) unsigned int*)(l),
        16, 0, 0);
}

// Problem constants: B=4, NQ=NC=4096, D=1024, H=16, HD=64
#define NROW 16384
#define DDIM 1024

// =====================================================================
// LayerNorm: f32 row (1024) -> bf16 row.
// =====================================================================
__global__ __launch_bounds__(256) void ln_kernel(
    const float* __restrict__ query, const float* __restrict__ context,
    const float* __restrict__ lnq_g, const float* __restrict__ lnq_b,
    const float* __restrict__ lnk_g, const float* __restrict__ lnk_b,
    unsigned short* __restrict__ qln, unsigned short* __restrict__ cln)
{
    const int row = blockIdx.x;
    const bool isq = row < NROW;
    const int r = isq ? row : row - NROW;
    const float* src = (isq ? query : context) + (size_t)r * DDIM;
    const float* g   = isq ? lnq_g : lnk_g;
    const float* bb  = isq ? lnq_b : lnk_b;
    unsigned short* dst = (isq ? qln : cln) + (size_t)r * DDIM;

    const int tid = threadIdx.x;
    f32x4 x = *(const f32x4*)(src + tid * 4);
    float s  = x[0] + x[1] + x[2] + x[3];
    float sq = x[0]*x[0] + x[1]*x[1] + x[2]*x[2] + x[3]*x[3];
#pragma unroll
    for (int off = 32; off; off >>= 1) {
        s  += __shfl_xor(s, off);
        sq += __shfl_xor(sq, off);
    }
    __shared__ float red[8];
    const int lane = tid & 63, w = tid >> 6;
    if (lane == 0) { red[w] = s; red[4 + w] = sq; }
    __syncthreads();
    s  = red[0] + red[1] + red[2] + red[3];
    sq = red[4] + red[5] + red[6] + red[7];
    const float mu  = s * (1.0f / DDIM);
    const float var = sq * (1.0f / DDIM) - mu * mu;
    const float rstd = rsqrtf(var + 1e-5f);

    f32x4 gv = *(const f32x4*)(g + tid * 4);
    f32x4 bv = *(const f32x4*)(bb + tid * 4);
    short4v o;
#pragma unroll
    for (int j = 0; j < 4; ++j)
        o[j] = (short)f2bf((x[j] - mu) * rstd * gv[j] + bv[j]);
    *(short4v*)(dst + tid * 4) = o;
}

// =====================================================================
// Weight convert f32 -> bf16 (WQ, WK, WV, WO contiguous)
// =====================================================================
__global__ __launch_bounds__(256) void conv_w(
    const float* __restrict__ a, const float* __restrict__ b,
    const float* __restrict__ c, const float* __restrict__ d,
    unsigned short* __restrict__ out)
{
    const int i = blockIdx.x * 256 + threadIdx.x;
    const int mat = i >> 18;
    const int idx = (i & 262143) * 4;
    const float* src = mat == 0 ? a : mat == 1 ? b : mat == 2 ? c : d;
    f32x4 v = *(const f32x4*)(src + idx);
    short4v o;
#pragma unroll
    for (int j = 0; j < 4; ++j) o[j] = (short)f2bf(v[j]);
    *(short4v*)(out + (size_t)mat * 1048576 + idx) = o;
}

// =====================================================================
// 128x128-tile GEMM core, BK=32, single-buffered LDS (16 KiB), 256 thr /
// 4 waves (2x2, wave-tile 64x64), m97-exact 2-barrier loop. The lever vs
// round 1: __launch_bounds__(256,4) forces total unified regs <=128/wave
// (acc 64 AGPR + ~55 VGPR) -> 4 waves/SIMD -> 4 blocks/CU co-resident ->
// cross-block TLP hides the per-iter vmcnt(0) drain (m114).
// C = A @ Bm^T; both operands row-major K-contiguous bf16, K=1024.
// BK=32 rows are 64 B -> ds_read 2-way bank aliasing only (free, m136):
// no swizzle needed.
// =====================================================================
template <typename EPI>
DEV void gemm128(unsigned short* __restrict__ sA,
                 unsigned short* __restrict__ sB,
                 const unsigned short* __restrict__ Ap,
                 const unsigned short* __restrict__ Bp,
                 int m0, int n0, EPI epi)
{
    const int tid = threadIdx.x;
    const int lane = tid & 63, w = tid >> 6;
    const int wr = w >> 1, wc = w & 1;
    const int lr = lane & 15, lg = lane >> 4;

    // staging: 128 rows x 32 cols per matrix; thread covers rows (tid>>2)
    // and (tid>>2)+64, 16B chunk (tid&3). Linear LDS (gload_lds constraint).
    const int srow = tid >> 2, sch = tid & 3;
    const unsigned short* gA0 = Ap + (size_t)(m0 + srow) * 1024 + sch * 8;
    const unsigned short* gB0 = Bp + (size_t)(n0 + srow) * 1024 + sch * 8;
    unsigned short* dA = sA + tid * 8;
    unsigned short* dB = sB + tid * 8;

    f32x4 acc[4][4];
#pragma unroll
    for (int i = 0; i < 4; ++i)
#pragma unroll
        for (int j = 0; j < 4; ++j)
#pragma unroll
            for (int e = 0; e < 4; ++e) acc[i][j][e] = 0.0f;

    for (int t = 0; t < 32; ++t) {
        const int ko = t * 32;
        gload_lds16(gA0 + ko, dA);
        gload_lds16(gA0 + ko + (size_t)65536, dA + 2048);   // rows +64
        gload_lds16(gB0 + ko, dB);
        gload_lds16(gB0 + ko + (size_t)65536, dB + 2048);
        asm volatile("s_waitcnt vmcnt(0)" ::: "memory");
        __syncthreads();

        short8 af[4], bf[4];
#pragma unroll
        for (int mt = 0; mt < 4; ++mt)
            af[mt] = *(const short8*)&sA[(wr * 64 + mt * 16 + lr) * 32 + lg * 8];
#pragma unroll
        for (int nt = 0; nt < 4; ++nt)
            bf[nt] = *(const short8*)&sB[(wc * 64 + nt * 16 + lr) * 32 + lg * 8];
#pragma unroll
        for (int mt = 0; mt < 4; ++mt)
#pragma unroll
            for (int nt = 0; nt < 4; ++nt)
                acc[mt][nt] = __builtin_amdgcn_mfma_f32_16x16x32_bf16(
                    af[mt], bf[nt], acc[mt][nt], 0, 0, 0);
        __syncthreads();
    }

#pragma unroll
    for (int mt = 0; mt < 4; ++mt)
#pragma unroll
        for (int nt = 0; nt < 4; ++nt) {
            const int col = n0 + wc * 64 + nt * 16 + lr;
#pragma unroll
            for (int i = 0; i < 4; ++i) {
                const int row = m0 + wr * 64 + mt * 16 + lg * 4 + i;
                epi(row, col, acc[mt][nt][i]);
            }
        }
}

// ---- merged projections: Q-proj (1024 tiles) + KV-proj (2048 tiles) ----
__global__ __launch_bounds__(256, 4) void gemm_qkv(
    const unsigned short* __restrict__ QLN, const unsigned short* __restrict__ WQ,
    const unsigned short* __restrict__ CLN, const unsigned short* __restrict__ WKV,
    unsigned short* __restrict__ Qm, unsigned short* __restrict__ KVT,
    const float* __restrict__ q_b, const float* __restrict__ k_b,
    const float* __restrict__ v_b)
{
    __shared__ __attribute__((aligned(16))) unsigned short sA[128 * 32];
    __shared__ __attribute__((aligned(16))) unsigned short sB[128 * 32];

    const int bid = blockIdx.x;                  // 3072 blocks
    const int l = (bid & 7) * 384 + (bid >> 3);  // XCD-chunked (3072 % 8 == 0)

    if (l < 1024) {
        // Qm = elu1(QLN @ WQ^T + q_b) : M=16384, N=1024
        const int m0 = (l >> 3) * 128, n0 = (l & 7) * 128;
        gemm128(sA, sB, QLN, WQ, m0, n0,
            [&](int row, int col, float v) {
                v = elu1(v + q_b[col]);
                Qm[(size_t)row * 1024 + col] = f2bf(v);
            });
    } else {
        // KVT = f(WKV @ CLN^T + bias) : M=2048 (K rows 0-1023, V rows 1024-2047)
        const int r = l - 1024;                  // 0..2047
        const int m0 = (r & 15) * 128, n0 = (r >> 4) * 128;
        gemm128(sA, sB, WKV, CLN, m0, n0,
            [&](int row, int col, float v) {
                if (row < 1024) v = elu1(v + k_b[row]);
                else            v = v + v_b[row - 1024];
                KVT[(size_t)row * NROW + col] = f2bf(v);
            });
    }
}

// ---- output projection: out = A2 @ WO^T + o_b + resid (f32) ----
__global__ __launch_bounds__(256, 4) void gemm_out(
    const unsigned short* __restrict__ A2, const unsigned short* __restrict__ WO,
    float* __restrict__ Out, const float* __restrict__ o_b,
    const float* __restrict__ resid)
{
    __shared__ __attribute__((aligned(16))) unsigned short sA[128 * 32];
    __shared__ __attribute__((aligned(16))) unsigned short sB[128 * 32];

    const int bid = blockIdx.x;                  // 1024 blocks
    const int l = (bid & 7) * 128 + (bid >> 3);  // XCD-chunked
    const int m0 = (l >> 3) * 128, n0 = (l & 7) * 128;
    gemm128(sA, sB, A2, WO, m0, n0,
        [&](int row, int col, float v) {
            Out[(size_t)row * 1024 + col] =
                v + o_b[col] + resid[(size_t)row * 1024 + col];
        });
}

// =====================================================================
// KV partials: KVTp[s][bh][e][d] = sum over n-chunk of V[n,e]*K[n,d]
// =====================================================================
__global__ __launch_bounds__(256) void kv_kernel(
    const unsigned short* __restrict__ VT, const unsigned short* __restrict__ KT,
    float* __restrict__ KVTp)
{
    const int bh = blockIdx.x, sp = blockIdx.y;
    const int b = bh >> 4, h = bh & 15;
    const int tid = threadIdx.x, lane = tid & 63, w = tid >> 6;
    const int lr = lane & 15, lg = lane >> 4;

    f32x4 acc[4][4];
#pragma unroll
    for (int i = 0; i < 4; ++i)
#pragma unroll
        for (int j = 0; j < 4; ++j)
#pragma unroll
            for (int e = 0; e < 4; ++e) acc[i][j][e] = 0.0f;

    const size_t colbase = (size_t)b * 4096 + sp * 1024 + w * 256 + lg * 8;
    const unsigned short* va = VT + (size_t)(h * 64 + lr) * NROW + colbase;
    const unsigned short* ka = KT + (size_t)(h * 64 + lr) * NROW + colbase;

    for (int ks = 0; ks < 8; ++ks) {
        short8 af[4], bfv[4];
#pragma unroll
        for (int mt = 0; mt < 4; ++mt)
            af[mt] = *(const short8*)(va + (size_t)mt * 16 * NROW + ks * 32);
#pragma unroll
        for (int nt = 0; nt < 4; ++nt)
            bfv[nt] = *(const short8*)(ka + (size_t)nt * 16 * NROW + ks * 32);
#pragma unroll
        for (int mt = 0; mt < 4; ++mt)
#pragma unroll
            for (int nt = 0; nt < 4; ++nt)
                acc[mt][nt] = __builtin_amdgcn_mfma_f32_16x16x32_bf16(
                    af[mt], bfv[nt], acc[mt][nt], 0, 0, 0);
    }

    __shared__ float red4[4][4096];
#pragma unroll
    for (int mt = 0; mt < 4; ++mt)
#pragma unroll
        for (int nt = 0; nt < 4; ++nt)
#pragma unroll
            for (int i = 0; i < 4; ++i)
                red4[w][(mt * 16 + lg * 4 + i) * 64 + nt * 16 + lr] = acc[mt][nt][i];
    __syncthreads();
    float* out = KVTp + ((size_t)sp * 64 + bh) * 4096;
    for (int i = tid; i < 4096; i += 256)
        out[i] = red4[0][i] + red4[1][i] + red4[2][i] + red4[3][i];
}

// =====================================================================
// Ksum[bh][d] = sum_n KT[h*64+d][b*4096+n]
// =====================================================================
__global__ __launch_bounds__(256) void ksum_kernel(
    const unsigned short* __restrict__ KT, float* __restrict__ Ksum)
{
    const int bh = blockIdx.x, quad = blockIdx.y;
    const int b = bh >> 4, h = bh & 15;
    const int tid = threadIdx.x, lane = tid & 63, w = tid >> 6;
    const int dbase = quad * 16 + w * 4;
#pragma unroll
    for (int dd = 0; dd < 4; ++dd) {
        const int d = dbase + dd;
        const unsigned short* p = KT + (size_t)(h * 64 + d) * NROW + b * 4096 + lane * 8;
        float s = 0.0f;
#pragma unroll
        for (int it = 0; it < 8; ++it) {
            short8 v = *(const short8*)(p + it * 512);
#pragma unroll
            for (int j = 0; j < 8; ++j) s += bf2f((unsigned short)v[j]);
        }
#pragma unroll
        for (int off = 32; off; off >>= 1) s += __shfl_xor(s, off);
        if (lane == 0) Ksum[bh * 64 + d] = s;
    }
}

// =====================================================================
// invZ[n][h] = 1 / max(sum_d Q[n][h*64+d]*Ksum[bh][d], 1e-6)
// =====================================================================
__global__ __launch_bounds__(256) void z_kernel(
    const unsigned short* __restrict__ Q, const float* __restrict__ Ksum,
    float* __restrict__ invZ)
{
    const int gid = blockIdx.x * 256 + threadIdx.x;
    const int n = gid >> 4, h = gid & 15;
    const int b = n >> 12;
    const unsigned short* q = Q + (size_t)n * DDIM + h * 64;
    const float* ks = Ksum + ((b << 4) + h) * 64;
    float z = 0.0f;
#pragma unroll
    for (int it = 0; it < 8; ++it) {
        short8 v = *(const short8*)(q + it * 8);
#pragma unroll
        for (int j = 0; j < 8; ++j) z += bf2f((unsigned short)v[j]) * ks[it * 8 + j];
    }
    invZ[gid] = 1.0f / fmaxf(z, 1e-6f);
}

// =====================================================================
// A2[n][h*64+e] = (sum_d Q[n][h*64+d] * KV[d][e]) * invZ[n][h]
// =====================================================================
__global__ __launch_bounds__(256) void a2_kernel(
    const unsigned short* __restrict__ Q, const float* __restrict__ KVTp,
    const float* __restrict__ invZ, unsigned short* __restrict__ A2)
{
    const int m0 = blockIdx.x * 128, h = blockIdx.y;
    const int b = m0 >> 12, bh = (b << 4) + h;
    const int tid = threadIdx.x, lane = tid & 63, w = tid >> 6;
    const int wr = w >> 1, wc = w & 1;
    const int lr = lane & 15, lg = lane >> 4;

    f32x4 acc[4][2];
#pragma unroll
    for (int i = 0; i < 4; ++i)
#pragma unroll
        for (int j = 0; j < 2; ++j)
#pragma unroll
            for (int e = 0; e < 4; ++e) acc[i][j][e] = 0.0f;

    const unsigned short* qa = Q + (size_t)(m0 + wr * 64 + lr) * DDIM + h * 64 + lg * 8;
    const float* kvb = KVTp + (size_t)bh * 4096 + (wc * 32 + lr) * 64 + lg * 8;

#pragma unroll
    for (int ks = 0; ks < 2; ++ks) {
        short8 af[4];
#pragma unroll
        for (int mt = 0; mt < 4; ++mt)
            af[mt] = *(const short8*)(qa + (size_t)mt * 16 * DDIM + ks * 32);
        short8 bfv[2];
#pragma unroll
        for (int nt = 0; nt < 2; ++nt) {
            const float* p = kvb + nt * 16 * 64 + ks * 32;
            short8 t;
#pragma unroll
            for (int j = 0; j < 8; ++j) {
                float v = p[j] + p[j + 262144] + p[j + 2 * 262144] + p[j + 3 * 262144];
                t[j] = (short)f2bf(v);
            }
            bfv[nt] = t;
        }
#pragma unroll
        for (int mt = 0; mt < 4; ++mt)
#pragma unroll
            for (int nt = 0; nt < 2; ++nt)
                acc[mt][nt] = __builtin_amdgcn_mfma_f32_16x16x32_bf16(
                    af[mt], bfv[nt], acc[mt][nt], 0, 0, 0);
    }

#pragma unroll
    for (int mt = 0; mt < 4; ++mt)
#pragma unroll
        for (int nt = 0; nt < 2; ++nt)
#pragma unroll
            for (int i = 0; i < 4; ++i) {
                const int row = m0 + wr * 64 + mt * 16 + lg * 4 + i;
                const int col = h * 64 + wc * 32 + nt * 16 + lr;
                const float v = acc[mt][nt][i] * invZ[row * 16 + h];
                A2[(size_t)row * DDIM + col] = f2bf(v);
            }
}

// =====================================================================
// host
// =====================================================================
extern "C" void kernel_launch(void* const* d_in, const int* in_sizes, int n_in,
                              void* d_out, int out_size, void* d_ws, size_t ws_size,
                              hipStream_t stream)
{
    const float* query   = (const float*)d_in[0];
    const float* context = (const float*)d_in[1];
    const float* q_w = (const float*)d_in[2];
    const float* q_b = (const float*)d_in[3];
    const float* k_w = (const float*)d_in[4];
    const float* k_b = (const float*)d_in[5];
    const float* v_w = (const float*)d_in[6];
    const float* v_b = (const float*)d_in[7];
    const float* o_w = (const float*)d_in[8];
    const float* o_b = (const float*)d_in[9];
    const float* lnq_g = (const float*)d_in[10];
    const float* lnq_b = (const float*)d_in[11];
    const float* lnk_g = (const float*)d_in[12];
    const float* lnk_b = (const float*)d_in[13];

    char* ws = (char*)d_ws;
    unsigned short* WQ  = (unsigned short*)(ws);                    // 2 MiB
    unsigned short* WKV = (unsigned short*)(ws + (2u << 20));       // WK;WV 4 MiB
    unsigned short* WO  = (unsigned short*)(ws + (6u << 20));
    unsigned short* QLN = (unsigned short*)(ws + (8u << 20));       // 32 MiB
    unsigned short* CLN = (unsigned short*)(ws + (40u << 20));
    unsigned short* Qm  = (unsigned short*)(ws + (72u << 20));
    unsigned short* KT  = (unsigned short*)(ws + (104u << 20));     // rows 0-1023 of KVT
    unsigned short* VT  = (unsigned short*)(ws + (136u << 20));     // rows 1024-2047
    float* KVTp = (float*)(ws + (168u << 20));
    float* Ksum = (float*)(ws + (172u << 20));
    float* invZ = (float*)(ws + (173u << 20));
    unsigned short* A2 = QLN;                                       // alias

    conv_w<<<4096, 256, 0, stream>>>(q_w, k_w, v_w, o_w, WQ);
    ln_kernel<<<2 * NROW, 256, 0, stream>>>(query, context, lnq_g, lnq_b,
                                            lnk_g, lnk_b, QLN, CLN);
    gemm_qkv<<<3072, 256, 0, stream>>>(QLN, WQ, CLN, WKV, Qm, KT,
                                       q_b, k_b, v_b);
    kv_kernel<<<dim3(64, 4), 256, 0, stream>>>(VT, KT, KVTp);
    ksum_kernel<<<dim3(64, 4), 256, 0, stream>>>(KT, Ksum);
    z_kernel<<<1024, 256, 0, stream>>>(Qm, Ksum, invZ);
    a2_kernel<<<dim3(128, 16), 256, 0, stream>>>(Qm, KVTp, invZ, A2);
    gemm_out<<<1024, 256, 0, stream>>>(A2, WO, (float*)d_out, o_b, query);
}

// Round 9
// 315.666 us; speedup vs baseline: 1.0335x; 1.0335x over previous
//
#include <hip/hip_runtime.h>

#define DEV __device__ __forceinline__

typedef __attribute__((ext_vector_type(8))) short short8;
typedef __attribute__((ext_vector_type(4))) short short4v;
typedef __attribute__((ext_vector_type(4))) float f32x4;

// ---------- bf16 helpers ----------
DEV float bf2f(unsigned short u) { return __uint_as_float(((unsigned int)u) << 16); }
DEV unsigned short f2bf(float f) {
    unsigned int u = __float_as_uint(f);
    u += 0x7FFFu + ((u >> 16) & 1u);   // RNE
    return (unsigned short)(u >> 16);
}

DEV float elu1(float v) { return v > 0.0f ? v + 1.0f : __expf(v); }

// ---------- async global->LDS, 16B per lane ----------
DEV void gload_lds16(const void* g, void* l) {
    __builtin_amdgcn_global_load_lds(
        (__attribute__((address_space(1))) unsigned int*)(g),
        (__attribute__((address_space(3))) unsigned int*)(l),
        16, 0, 0);
}

// Problem constants: B=4, NQ=NC=4096, D=1024, H=16, HD=64
#define NROW 16384
#define DDIM 1024

// =====================================================================
// LayerNorm: f32 row (1024) -> bf16 row.
// =====================================================================
__global__ __launch_bounds__(256) void ln_kernel(
    const float* __restrict__ query, const float* __restrict__ context,
    const float* __restrict__ lnq_g, const float* __restrict__ lnq_b,
    const float* __restrict__ lnk_g, const float* __restrict__ lnk_b,
    unsigned short* __restrict__ qln, unsigned short* __restrict__ cln)
{
    const int row = blockIdx.x;
    const bool isq = row < NROW;
    const int r = isq ? row : row - NROW;
    const float* src = (isq ? query : context) + (size_t)r * DDIM;
    const float* g   = isq ? lnq_g : lnk_g;
    const float* bb  = isq ? lnq_b : lnk_b;
    unsigned short* dst = (isq ? qln : cln) + (size_t)r * DDIM;

    const int tid = threadIdx.x;
    f32x4 x = *(const f32x4*)(src + tid * 4);
    float s  = x[0] + x[1] + x[2] + x[3];
    float sq = x[0]*x[0] + x[1]*x[1] + x[2]*x[2] + x[3]*x[3];
#pragma unroll
    for (int off = 32; off; off >>= 1) {
        s  += __shfl_xor(s, off);
        sq += __shfl_xor(sq, off);
    }
    __shared__ float red[8];
    const int lane = tid & 63, w = tid >> 6;
    if (lane == 0) { red[w] = s; red[4 + w] = sq; }
    __syncthreads();
    s  = red[0] + red[1] + red[2] + red[3];
    sq = red[4] + red[5] + red[6] + red[7];
    const float mu  = s * (1.0f / DDIM);
    const float var = sq * (1.0f / DDIM) - mu * mu;
    const float rstd = rsqrtf(var + 1e-5f);

    f32x4 gv = *(const f32x4*)(g + tid * 4);
    f32x4 bv = *(const f32x4*)(bb + tid * 4);
    short4v o;
#pragma unroll
    for (int j = 0; j < 4; ++j)
        o[j] = (short)f2bf((x[j] - mu) * rstd * gv[j] + bv[j]);
    *(short4v*)(dst + tid * 4) = o;
}

// =====================================================================
// Weight convert f32 -> bf16 (WQ, WK, WV, WO contiguous)
// =====================================================================
__global__ __launch_bounds__(256) void conv_w(
    const float* __restrict__ a, const float* __restrict__ b,
    const float* __restrict__ c, const float* __restrict__ d,
    unsigned short* __restrict__ out)
{
    const int i = blockIdx.x * 256 + threadIdx.x;
    const int mat = i >> 18;
    const int idx = (i & 262143) * 4;
    const float* src = mat == 0 ? a : mat == 1 ? b : mat == 2 ? c : d;
    f32x4 v = *(const f32x4*)(src + idx);
    short4v o;
#pragma unroll
    for (int j = 0; j < 4; ++j) o[j] = (short)f2bf(v[j]);
    *(short4v*)(out + (size_t)mat * 1048576 + idx) = o;
}

// =====================================================================
// 128x128-tile GEMM core, BK=64, single-buffered LDS (32 KiB), 256 thr /
// 4 waves (2x2, wave-tile 64x64), 16 K-steps.
//  - BK=64 rows (128 B) + 8-chunk XOR source/read swizzle -> 0 bank
//    conflicts (round-7-validated formulas).
//  - frags read per-kk (32 live VGPR) -> total ~120 unified regs ->
//    4 waves/SIMD; 32 KiB LDS -> up to 5 blocks/CU (m114 overlap).
//  - STG(t+1) issued after the all-frags-read barrier, before the kk=1
//    MFMA half: staging latency hides under MFMA + other blocks.
// C = A @ Bm^T; both operands row-major K-contiguous bf16, K=1024.
// =====================================================================
template <typename EPI>
DEV void gemm128(unsigned short* __restrict__ sA,
                 unsigned short* __restrict__ sB,
                 const unsigned short* __restrict__ Ap,
                 const unsigned short* __restrict__ Bp,
                 int m0, int n0, EPI epi)
{
    const int tid = threadIdx.x;
    const int lane = tid & 63, w = tid >> 6;
    const int wr = w >> 1, wc = w & 1;
    const int lr = lane & 15, lg = lane >> 4;

    // staging: rows (tid>>3) + 32j, chunk (tid&7) of 8 x 16B per 128B row;
    // source chunk XOR-swizzled so swizzled LDS reads return linear data.
    const int srow = tid >> 3;
    const int cswz = (tid & 7) ^ (srow & 7);
    const unsigned short* gA0 = Ap + (size_t)(m0 + srow) * 1024 + cswz * 8;
    const unsigned short* gB0 = Bp + (size_t)(n0 + srow) * 1024 + cswz * 8;
    unsigned short* dA = sA + tid * 8;
    unsigned short* dB = sB + tid * 8;

    // read-side swizzled chunk offsets (row parity = lr&7, chunk = kk*4+lg)
    const int sw0 = ((0 + lg) ^ (lr & 7)) * 8;
    const int sw1 = ((4 + lg) ^ (lr & 7)) * 8;

    f32x4 acc[4][4];
#pragma unroll
    for (int i = 0; i < 4; ++i)
#pragma unroll
        for (int j = 0; j < 4; ++j)
#pragma unroll
            for (int e = 0; e < 4; ++e) acc[i][j][e] = 0.0f;

    // stage full 128x64 A+B tiles for K-step T (8 gload_lds / thread)
#define STG8(T)                                                               \
    {                                                                         \
        const int ko = (T) * 64;                                              \
        _Pragma("unroll")                                                     \
        for (int j = 0; j < 4; ++j) {                                         \
            gload_lds16(gA0 + ko + (size_t)j * 32768, dA + j * 2048);         \
            gload_lds16(gB0 + ko + (size_t)j * 32768, dB + j * 2048);         \
        }                                                                     \
    }

    STG8(0);
    for (int t = 0; t < 16; ++t) {
        asm volatile("s_waitcnt vmcnt(0)" ::: "memory");
        __builtin_amdgcn_s_barrier();

        // ---- kk = 0: read 8 frags, MFMA 16 ----
        short8 af[4], bf[4];
#pragma unroll
        for (int mt = 0; mt < 4; ++mt)
            af[mt] = *(const short8*)&sA[(wr * 64 + mt * 16 + lr) * 64 + sw0];
#pragma unroll
        for (int nt = 0; nt < 4; ++nt)
            bf[nt] = *(const short8*)&sB[(wc * 64 + nt * 16 + lr) * 64 + sw0];
        __builtin_amdgcn_s_setprio(1);
#pragma unroll
        for (int mt = 0; mt < 4; ++mt)
#pragma unroll
            for (int nt = 0; nt < 4; ++nt)
                acc[mt][nt] = __builtin_amdgcn_mfma_f32_16x16x32_bf16(
                    af[mt], bf[nt], acc[mt][nt], 0, 0, 0);
        __builtin_amdgcn_s_setprio(0);

        // ---- kk = 1: read remaining 8 frags ----
#pragma unroll
        for (int mt = 0; mt < 4; ++mt)
            af[mt] = *(const short8*)&sA[(wr * 64 + mt * 16 + lr) * 64 + sw1];
#pragma unroll
        for (int nt = 0; nt < 4; ++nt)
            bf[nt] = *(const short8*)&sB[(wc * 64 + nt * 16 + lr) * 64 + sw1];
        asm volatile("s_waitcnt lgkmcnt(0)" ::: "memory");  // all my reads done
        __builtin_amdgcn_s_barrier();                       // all waves done
        if (t < 15) STG8(t + 1);                            // overlaps MFMA below
        __builtin_amdgcn_s_setprio(1);
#pragma unroll
        for (int mt = 0; mt < 4; ++mt)
#pragma unroll
            for (int nt = 0; nt < 4; ++nt)
                acc[mt][nt] = __builtin_amdgcn_mfma_f32_16x16x32_bf16(
                    af[mt], bf[nt], acc[mt][nt], 0, 0, 0);
        __builtin_amdgcn_s_setprio(0);
    }
#undef STG8

#pragma unroll
    for (int mt = 0; mt < 4; ++mt)
#pragma unroll
        for (int nt = 0; nt < 4; ++nt) {
            const int col = n0 + wc * 64 + nt * 16 + lr;
#pragma unroll
            for (int i = 0; i < 4; ++i) {
                const int row = m0 + wr * 64 + mt * 16 + lg * 4 + i;
                epi(row, col, acc[mt][nt][i]);
            }
        }
}

// ---- merged projections: Q-proj (1024 tiles) + KV-proj (2048 tiles) ----
__global__ __launch_bounds__(256, 4) void gemm_qkv(
    const unsigned short* __restrict__ QLN, const unsigned short* __restrict__ WQ,
    const unsigned short* __restrict__ CLN, const unsigned short* __restrict__ WKV,
    unsigned short* __restrict__ Qm, unsigned short* __restrict__ KVT,
    const float* __restrict__ q_b, const float* __restrict__ k_b,
    const float* __restrict__ v_b)
{
    __shared__ __attribute__((aligned(16))) unsigned short sA[128 * 64];
    __shared__ __attribute__((aligned(16))) unsigned short sB[128 * 64];

    const int bid = blockIdx.x;                  // 3072 blocks
    const int l = (bid & 7) * 384 + (bid >> 3);  // XCD-chunked (3072 % 8 == 0)

    if (l < 1024) {
        // Qm = elu1(QLN @ WQ^T + q_b) : M=16384, N=1024
        const int m0 = (l >> 3) * 128, n0 = (l & 7) * 128;
        gemm128(sA, sB, QLN, WQ, m0, n0,
            [&](int row, int col, float v) {
                v = elu1(v + q_b[col]);
                Qm[(size_t)row * 1024 + col] = f2bf(v);
            });
    } else {
        // KVT = f(WKV @ CLN^T + bias) : M=2048 (K rows 0-1023, V rows 1024-2047)
        const int r = l - 1024;                  // 0..2047
        const int m0 = (r & 15) * 128, n0 = (r >> 4) * 128;
        gemm128(sA, sB, WKV, CLN, m0, n0,
            [&](int row, int col, float v) {
                if (row < 1024) v = elu1(v + k_b[row]);
                else            v = v + v_b[row - 1024];
                KVT[(size_t)row * NROW + col] = f2bf(v);
            });
    }
}

// ---- output projection: out = A2 @ WO^T + o_b + resid (f32) ----
__global__ __launch_bounds__(256, 4) void gemm_out(
    const unsigned short* __restrict__ A2, const unsigned short* __restrict__ WO,
    float* __restrict__ Out, const float* __restrict__ o_b,
    const float* __restrict__ resid)
{
    __shared__ __attribute__((aligned(16))) unsigned short sA[128 * 64];
    __shared__ __attribute__((aligned(16))) unsigned short sB[128 * 64];

    const int bid = blockIdx.x;                  // 1024 blocks
    const int l = (bid & 7) * 128 + (bid >> 3);  // XCD-chunked
    const int m0 = (l >> 3) * 128, n0 = (l & 7) * 128;
    gemm128(sA, sB, A2, WO, m0, n0,
        [&](int row, int col, float v) {
            Out[(size_t)row * 1024 + col] =
                v + o_b[col] + resid[(size_t)row * 1024 + col];
        });
}

// =====================================================================
// KV partials + fused Ksum partials.
// KVTp[sp][bh][e][d] = sum over n-chunk of V[n,e]*K[n,d]
// Ksump[sp][bh][d]   = sum over n-chunk of K[n,d]
// =====================================================================
__global__ __launch_bounds__(256) void kv_kernel(
    const unsigned short* __restrict__ VT, const unsigned short* __restrict__ KT,
    float* __restrict__ KVTp, float* __restrict__ Ksump)
{
    const int bh = blockIdx.x, sp = blockIdx.y;
    const int b = bh >> 4, h = bh & 15;
    const int tid = threadIdx.x, lane = tid & 63, w = tid >> 6;
    const int lr = lane & 15, lg = lane >> 4;

    f32x4 acc[4][4];
#pragma unroll
    for (int i = 0; i < 4; ++i)
#pragma unroll
        for (int j = 0; j < 4; ++j)
#pragma unroll
            for (int e = 0; e < 4; ++e) acc[i][j][e] = 0.0f;
    float kp[4] = {0.0f, 0.0f, 0.0f, 0.0f};

    const size_t colbase = (size_t)b * 4096 + sp * 1024 + w * 256 + lg * 8;
    const unsigned short* va = VT + (size_t)(h * 64 + lr) * NROW + colbase;
    const unsigned short* ka = KT + (size_t)(h * 64 + lr) * NROW + colbase;

    for (int ks = 0; ks < 8; ++ks) {
        short8 af[4], bfv[4];
#pragma unroll
        for (int mt = 0; mt < 4; ++mt)
            af[mt] = *(const short8*)(va + (size_t)mt * 16 * NROW + ks * 32);
#pragma unroll
        for (int nt = 0; nt < 4; ++nt)
            bfv[nt] = *(const short8*)(ka + (size_t)nt * 16 * NROW + ks * 32);
#pragma unroll
        for (int mt = 0; mt < 4; ++mt)
#pragma unroll
            for (int nt = 0; nt < 4; ++nt)
                acc[mt][nt] = __builtin_amdgcn_mfma_f32_16x16x32_bf16(
                    af[mt], bfv[nt], acc[mt][nt], 0, 0, 0);
        // fused Ksum: bfv[nt][j] = K[n, d=nt*16+lr]
#pragma unroll
        for (int nt = 0; nt < 4; ++nt)
#pragma unroll
            for (int j = 0; j < 8; ++j)
                kp[nt] += bf2f((unsigned short)bfv[nt][j]);
    }

    // reduce kp across lg (lanes xor 16, 32 share lr)
#pragma unroll
    for (int nt = 0; nt < 4; ++nt) {
        kp[nt] += __shfl_xor(kp[nt], 16);
        kp[nt] += __shfl_xor(kp[nt], 32);
    }
    __shared__ float kred[4][64];
    if (lane < 16) {
#pragma unroll
        for (int nt = 0; nt < 4; ++nt) kred[w][nt * 16 + lane] = kp[nt];
    }

    __shared__ float red4[4][4096];
#pragma unroll
    for (int mt = 0; mt < 4; ++mt)
#pragma unroll
        for (int nt = 0; nt < 4; ++nt)
#pragma unroll
            for (int i = 0; i < 4; ++i)
                red4[w][(mt * 16 + lg * 4 + i) * 64 + nt * 16 + lr] = acc[mt][nt][i];
    __syncthreads();
    float* out = KVTp + ((size_t)sp * 64 + bh) * 4096;
    for (int i = tid; i < 4096; i += 256)
        out[i] = red4[0][i] + red4[1][i] + red4[2][i] + red4[3][i];
    if (tid < 64)
        Ksump[((size_t)sp * 64 + bh) * 64 + tid] =
            kred[0][tid] + kred[1][tid] + kred[2][tid] + kred[3][tid];
}

// =====================================================================
// invZ[n][h] = 1 / max(sum_d Q[n][h*64+d] * (sum_sp Ksump[sp][bh][d]), 1e-6)
// =====================================================================
__global__ __launch_bounds__(256) void z_kernel(
    const unsigned short* __restrict__ Q, const float* __restrict__ Ksump,
    float* __restrict__ invZ)
{
    const int gid = blockIdx.x * 256 + threadIdx.x;
    const int n = gid >> 4, h = gid & 15;
    const int b = n >> 12;
    const unsigned short* q = Q + (size_t)n * DDIM + h * 64;
    const float* k0 = Ksump + ((size_t)((b << 4) + h)) * 64;
    float z = 0.0f;
#pragma unroll
    for (int it = 0; it < 8; ++it) {
        short8 v = *(const short8*)(q + it * 8);
#pragma unroll
        for (int j = 0; j < 8; ++j) {
            const int d = it * 8 + j;
            const float ksv = k0[d] + k0[d + 4096] + k0[d + 8192] + k0[d + 12288];
            z += bf2f((unsigned short)v[j]) * ksv;
        }
    }
    invZ[gid] = 1.0f / fmaxf(z, 1e-6f);
}

// =====================================================================
// A2[n][h*64+e] = (sum_d Q[n][h*64+d] * KV[d][e]) * invZ[n][h]
// =====================================================================
__global__ __launch_bounds__(256) void a2_kernel(
    const unsigned short* __restrict__ Q, const float* __restrict__ KVTp,
    const float* __restrict__ invZ, unsigned short* __restrict__ A2)
{
    const int m0 = blockIdx.x * 128, h = blockIdx.y;
    const int b = m0 >> 12, bh = (b << 4) + h;
    const int tid = threadIdx.x, lane = tid & 63, w = tid >> 6;
    const int wr = w >> 1, wc = w & 1;
    const int lr = lane & 15, lg = lane >> 4;

    f32x4 acc[4][2];
#pragma unroll
    for (int i = 0; i < 4; ++i)
#pragma unroll
        for (int j = 0; j < 2; ++j)
#pragma unroll
            for (int e = 0; e < 4; ++e) acc[i][j][e] = 0.0f;

    const unsigned short* qa = Q + (size_t)(m0 + wr * 64 + lr) * DDIM + h * 64 + lg * 8;
    const float* kvb = KVTp + (size_t)bh * 4096 + (wc * 32 + lr) * 64 + lg * 8;

#pragma unroll
    for (int ks = 0; ks < 2; ++ks) {
        short8 af[4];
#pragma unroll
        for (int mt = 0; mt < 4; ++mt)
            af[mt] = *(const short8*)(qa + (size_t)mt * 16 * DDIM + ks * 32);
        short8 bfv[2];
#pragma unroll
        for (int nt = 0; nt < 2; ++nt) {
            const float* p = kvb + nt * 16 * 64 + ks * 32;
            short8 t;
#pragma unroll
            for (int j = 0; j < 8; ++j) {
                float v = p[j] + p[j + 262144] + p[j + 2 * 262144] + p[j + 3 * 262144];
                t[j] = (short)f2bf(v);
            }
            bfv[nt] = t;
        }
#pragma unroll
        for (int mt = 0; mt < 4; ++mt)
#pragma unroll
            for (int nt = 0; nt < 2; ++nt)
                acc[mt][nt] = __builtin_amdgcn_mfma_f32_16x16x32_bf16(
                    af[mt], bfv[nt], acc[mt][nt], 0, 0, 0);
    }

#pragma unroll
    for (int mt = 0; mt < 4; ++mt)
#pragma unroll
        for (int nt = 0; nt < 2; ++nt)
#pragma unroll
            for (int i = 0; i < 4; ++i) {
                const int row = m0 + wr * 64 + mt * 16 + lg * 4 + i;
                const int col = h * 64 + wc * 32 + nt * 16 + lr;
                const float v = acc[mt][nt][i] * invZ[row * 16 + h];
                A2[(size_t)row * DDIM + col] = f2bf(v);
            }
}

// =====================================================================
// host
// =====================================================================
extern "C" void kernel_launch(void* const* d_in, const int* in_sizes, int n_in,
                              void* d_out, int out_size, void* d_ws, size_t ws_size,
                              hipStream_t stream)
{
    const float* query   = (const float*)d_in[0];
    const float* context = (const float*)d_in[1];
    const float* q_w = (const float*)d_in[2];
    const float* q_b = (const float*)d_in[3];
    const float* k_w = (const float*)d_in[4];
    const float* k_b = (const float*)d_in[5];
    const float* v_w = (const float*)d_in[6];
    const float* v_b = (const float*)d_in[7];
    const float* o_w = (const float*)d_in[8];
    const float* o_b = (const float*)d_in[9];
    const float* lnq_g = (const float*)d_in[10];
    const float* lnq_b = (const float*)d_in[11];
    const float* lnk_g = (const float*)d_in[12];
    const float* lnk_b = (const float*)d_in[13];

    char* ws = (char*)d_ws;
    unsigned short* WQ  = (unsigned short*)(ws);                    // 2 MiB
    unsigned short* WKV = (unsigned short*)(ws + (2u << 20));       // WK;WV 4 MiB
    unsigned short* WO  = (unsigned short*)(ws + (6u << 20));
    unsigned short* QLN = (unsigned short*)(ws + (8u << 20));       // 32 MiB
    unsigned short* CLN = (unsigned short*)(ws + (40u << 20));
    unsigned short* Qm  = (unsigned short*)(ws + (72u << 20));
    unsigned short* KT  = (unsigned short*)(ws + (104u << 20));     // rows 0-1023 of KVT
    unsigned short* VT  = (unsigned short*)(ws + (136u << 20));     // rows 1024-2047
    float* KVTp  = (float*)(ws + (168u << 20));                     // 4 MiB
    float* Ksump = (float*)(ws + (172u << 20));                     // 64 KiB
    float* invZ  = (float*)(ws + (173u << 20));                     // 1 MiB
    unsigned short* A2 = QLN;                                       // alias

    conv_w<<<4096, 256, 0, stream>>>(q_w, k_w, v_w, o_w, WQ);
    ln_kernel<<<2 * NROW, 256, 0, stream>>>(query, context, lnq_g, lnq_b,
                                            lnk_g, lnk_b, QLN, CLN);
    gemm_qkv<<<3072, 256, 0, stream>>>(QLN, WQ, CLN, WKV, Qm, KT,
                                       q_b, k_b, v_b);
    kv_kernel<<<dim3(64, 4), 256, 0, stream>>>(VT, KT, KVTp, Ksump);
    z_kernel<<<1024, 256, 0, stream>>>(Qm, Ksump, invZ);
    a2_kernel<<<dim3(128, 16), 256, 0, stream>>>(Qm, KVTp, invZ, A2);
    gemm_out<<<1024, 256, 0, stream>>>(A2, WO, (float*)d_out, o_b, query);
}